// Round 5
// baseline (416.621 us; speedup 1.0000x reference)
//
#include <hip/hip_runtime.h>
#include <cstdint>

typedef unsigned short u16;
typedef unsigned int u32;
typedef __attribute__((ext_vector_type(8))) short bf16x8;
typedef __attribute__((ext_vector_type(4))) float f32x4;

typedef const u32 __attribute__((address_space(1)))* gp_t;
typedef u32 __attribute__((address_space(3)))* lp_t;

__device__ __forceinline__ u16 f2bf(float f) {
    union { float f; u32 u; } v; v.f = f;
    u32 r = v.u + 0x7FFFu + ((v.u >> 16) & 1u);   // RNE
    return (u16)(r >> 16);
}
__device__ __forceinline__ float bf2f(u16 h) {
    union { u32 u; float f; } v; v.u = ((u32)h) << 16;
    return v.f;
}

// ---------------- pack x (fp32 -> bf16), vectorized ----------------
__global__ void k_pack_x(const float* __restrict__ x, u16* __restrict__ xb, int n4) {
    int stride = gridDim.x * blockDim.x;
    for (int i = blockIdx.x * blockDim.x + threadIdx.x; i < n4; i += stride) {
        float4 v = ((const float4*)x)[i];
        ushort4 o;
        o.x = f2bf(v.x); o.y = f2bf(v.y); o.z = f2bf(v.z); o.w = f2bf(v.w);
        ((ushort4*)xb)[i] = o;
    }
}

// ---------------- transpose weight [1024][ncols] f32 -> [ncols][1024] bf16 ----
__global__ void k_transpose_w(const float* __restrict__ src, u16* __restrict__ dst, int ncols) {
    __shared__ float t[64][65];
    int ntn = ncols >> 6;
    int kb = (blockIdx.x / ntn) * 64;
    int nb = (blockIdx.x % ntn) * 64;
    for (int i = threadIdx.x; i < 4096; i += 256) {
        int r = i >> 6, c = i & 63;
        t[r][c] = src[(long)(kb + r) * ncols + nb + c];
    }
    __syncthreads();
    for (int i = threadIdx.x; i < 4096; i += 256) {
        int r = i >> 6, c = i & 63;
        dst[(long)(nb + r) * 1024 + kb + c] = f2bf(t[c][r]);
    }
}

// ---------------- 256x256 GEMM, BK=64, 4-phase/K-tile, reads pipelined 1 phase ----
// LDS elems (u16): A: [d][kh][256r][32k] d-stride 16384, kh-stride 8192; B at +32768.
// Phase p issues frag ds_reads for phase p+1 (double-buffered reg sets);
// vmcnt(6) at P1/P3 pre-barrier guarantees the half-tile pair read in the NEXT phase.
template<int EPI>
__global__ __launch_bounds__(512, 2) void k_gemm(
    const u16* __restrict__ A, const u16* __restrict__ Bt,
    int nTilesN,
    u16* __restrict__ qkT, u16* __restrict__ v_tm,
    float* __restrict__ outp, const float* __restrict__ bias)
{
    __shared__ uint4 smem4[8704];            // 139264 B (main loop uses first 128 KiB)
    u16* sm = (u16*)smem4;

    const int tid = threadIdx.x;
    const int wid = tid >> 6, lane = tid & 63;
    const int wr = wid >> 2, wc = wid & 3;   // 2M x 4N waves
    const int fr = lane & 15, sl = lane >> 4;

    const int nwg = gridDim.x;
    const int cpx = nwg >> 3;
    const int logical = (blockIdx.x & 7) * cpx + (blockIdx.x >> 3);
    const int bn = logical % nTilesN;
    const long bm = logical / nTilesN;
    const long m0 = bm * 256;
    const int n0 = bn * 256;

    // staging geometry: per stage-call a wave writes 2x1KB linear chunks (16 rows x 64B)
    const int srow = wid * 32 + (lane >> 2);
    const int kswz = (((lane & 3) ^ ((srow >> 1) & 3)) << 3);
    const u16* gA = A + (m0 + srow) * 1024L + kswz;
    const u16* gB = Bt + ((long)n0 + srow) * 1024L + kswz;
    const int ldst = wid * 1024;

    // frag-read geometry (XOR slot is row-invariant per lane)
    const int fxor = ((sl ^ ((fr >> 1) & 3)) << 3);
    const int aBase = (wr * 128 + fr) * 32 + fxor;      // + mi*512 + d*16384 + ks*8192
    const int bBase = 32768 + (wc * 64 + fr) * 32 + fxor;

    f32x4 acc[8][4];
#pragma unroll
    for (int i = 0; i < 8; ++i)
#pragma unroll
        for (int j = 0; j < 4; ++j) acc[i][j] = (f32x4){0.f, 0.f, 0.f, 0.f};

#define STAGE_A(d, kh, ts) do { \
    const u16* g_ = gA + (ts) * 64 + (kh) * 32; \
    u16* l_ = sm + (d) * 16384 + (kh) * 8192 + ldst; \
    __builtin_amdgcn_global_load_lds((gp_t)g_, (lp_t)l_, 16, 0, 0); \
    __builtin_amdgcn_global_load_lds((gp_t)(g_ + 16 * 1024), (lp_t)(l_ + 512), 16, 0, 0); \
} while (0)
#define STAGE_B(d, kh, ts) do { \
    const u16* g_ = gB + (ts) * 64 + (kh) * 32; \
    u16* l_ = sm + 32768 + (d) * 16384 + (kh) * 8192 + ldst; \
    __builtin_amdgcn_global_load_lds((gp_t)g_, (lp_t)l_, 16, 0, 0); \
    __builtin_amdgcn_global_load_lds((gp_t)(g_ + 16 * 1024), (lp_t)(l_ + 512), 16, 0, 0); \
} while (0)

    // prologue: T0.A.kh0, T0.B.kh0, T0.A.kh1, T0.B.kh1, T1.A.kh0, T1.B.kh0
    STAGE_A(0, 0, 0); STAGE_B(0, 0, 0);
    STAGE_A(0, 1, 0); STAGE_B(0, 1, 0);
    STAGE_A(1, 0, 1); STAGE_B(1, 0, 1);
    asm volatile("s_waitcnt vmcnt(8)" ::: "memory");   // T0.kh0 (A,B) landed
    __builtin_amdgcn_s_barrier();

    bf16x8 afX[4], afY[4], bfX[4], bfY[4];
    // prologue frag reads: T0 kh0 (consumed by P1 of T=0)
#pragma unroll
    for (int ni = 0; ni < 4; ++ni) bfX[ni] = *(const bf16x8*)(sm + bBase + ni * 512);
#pragma unroll
    for (int mi = 0; mi < 4; ++mi) afX[mi] = *(const bf16x8*)(sm + aBase + mi * 512);

#pragma unroll 2
    for (int T = 0; T < 16; ++T) {
        const int d = T & 1;
        const int t1 = (T + 1 < 16) ? T + 1 : 15;
        const int t2 = (T + 2 < 16) ? T + 2 : 15;
        const int base = d * 16384;
        const int nbase = (d ^ 1) * 16384;

        // ---- P1: MFMA(mh0,ks0); read mh1/ks0; vmcnt(6) covers T.kh1 for P2 reads ----
#pragma unroll
        for (int mi = 0; mi < 4; ++mi)
            afY[mi] = *(const bf16x8*)(sm + aBase + (4 + mi) * 512 + base);
        STAGE_A(d ^ 1, 1, t1);                          // (T+1).A.kh1
        asm volatile("s_waitcnt vmcnt(6)" ::: "memory");
        __builtin_amdgcn_s_barrier();
        __builtin_amdgcn_s_setprio(1);
#pragma unroll
        for (int mi = 0; mi < 4; ++mi)
#pragma unroll
            for (int ni = 0; ni < 4; ++ni)
                acc[mi][ni] = __builtin_amdgcn_mfma_f32_16x16x32_bf16(afX[mi], bfX[ni], acc[mi][ni], 0, 0, 0);
        __builtin_amdgcn_s_setprio(0);
        __builtin_amdgcn_s_barrier();

        // ---- P2: MFMA(mh1,ks0); read ks1 (bfY) + mh0/ks1 (afX) ----
#pragma unroll
        for (int ni = 0; ni < 4; ++ni)
            bfY[ni] = *(const bf16x8*)(sm + bBase + ni * 512 + base + 8192);
#pragma unroll
        for (int mi = 0; mi < 4; ++mi)
            afX[mi] = *(const bf16x8*)(sm + aBase + mi * 512 + base + 8192);
        STAGE_B(d ^ 1, 1, t1);                          // (T+1).B.kh1
        __builtin_amdgcn_s_barrier();
        __builtin_amdgcn_s_setprio(1);
#pragma unroll
        for (int mi = 0; mi < 4; ++mi)
#pragma unroll
            for (int ni = 0; ni < 4; ++ni)
                acc[mi + 4][ni] = __builtin_amdgcn_mfma_f32_16x16x32_bf16(afY[mi], bfX[ni], acc[mi + 4][ni], 0, 0, 0);
        __builtin_amdgcn_s_setprio(0);
        __builtin_amdgcn_s_barrier();

        // ---- P3: MFMA(mh0,ks1); read mh1/ks1; vmcnt(6) covers (T+1).kh0 for P4 reads ----
#pragma unroll
        for (int mi = 0; mi < 4; ++mi)
            afY[mi] = *(const bf16x8*)(sm + aBase + (4 + mi) * 512 + base + 8192);
        STAGE_A(d, 0, t2);                              // (T+2).A.kh0
        asm volatile("s_waitcnt vmcnt(6)" ::: "memory");
        __builtin_amdgcn_s_barrier();
        __builtin_amdgcn_s_setprio(1);
#pragma unroll
        for (int mi = 0; mi < 4; ++mi)
#pragma unroll
            for (int ni = 0; ni < 4; ++ni)
                acc[mi][ni] = __builtin_amdgcn_mfma_f32_16x16x32_bf16(afX[mi], bfY[ni], acc[mi][ni], 0, 0, 0);
        __builtin_amdgcn_s_setprio(0);
        __builtin_amdgcn_s_barrier();

        // ---- P4: MFMA(mh1,ks1); read (T+1) kh0 frags (bfX, afX) from other buffer ----
#pragma unroll
        for (int ni = 0; ni < 4; ++ni)
            bfX[ni] = *(const bf16x8*)(sm + bBase + ni * 512 + nbase);
#pragma unroll
        for (int mi = 0; mi < 4; ++mi)
            afX[mi] = *(const bf16x8*)(sm + aBase + mi * 512 + nbase);
        STAGE_B(d, 0, t2);                              // (T+2).B.kh0
        __builtin_amdgcn_s_barrier();
        __builtin_amdgcn_s_setprio(1);
#pragma unroll
        for (int mi = 0; mi < 4; ++mi)
#pragma unroll
            for (int ni = 0; ni < 4; ++ni)
                acc[mi + 4][ni] = __builtin_amdgcn_mfma_f32_16x16x32_bf16(afY[mi], bfY[ni], acc[mi + 4][ni], 0, 0, 0);
        __builtin_amdgcn_s_setprio(0);
        __builtin_amdgcn_s_barrier();
    }
#undef STAGE_A
#undef STAGE_B
    asm volatile("s_waitcnt vmcnt(0)" ::: "memory");   // drain tail junk stages
    __syncthreads();

    if (EPI == 0) {
        const long b = m0 >> 12;
        const int tok0 = (int)(m0 & 4095);
        if (n0 < 2048) {
            u16* piece = sm + wid * 8704;
#pragma unroll
            for (int mi = 0; mi < 8; ++mi)
#pragma unroll
                for (int ni = 0; ni < 4; ++ni) {
                    const int ch = ni * 16 + fr;
                    const int tk = mi * 16 + sl * 4;
                    ushort4 w;
                    w.x = f2bf(acc[mi][ni][0]); w.y = f2bf(acc[mi][ni][1]);
                    w.z = f2bf(acc[mi][ni][2]); w.w = f2bf(acc[mi][ni][3]);
                    *(ushort4*)(piece + ch * 136 + tk) = w;
                }
            __syncthreads();
#pragma unroll
            for (int i = 0; i < 16; ++i) {
                const int chunk = i * 512 + tid;
                const int row = chunk >> 4, c16 = chunk & 15;
                const int p = row >> 6, chl = row & 63;
                const int wrp = p >> 2, wcp = p & 3;
                const uint4 v = *(const uint4*)(sm + p * 8704 + chl * 136 + c16 * 8);
                *(uint4*)(qkT + ((b * 2048 + n0 + wcp * 64 + chl) * 4096L + tok0 + wrp * 128 + c16 * 8)) = v;
            }
        } else {
            u16* piece = sm + wid * 8704;
#pragma unroll
            for (int mi = 0; mi < 8; ++mi)
#pragma unroll
                for (int ni = 0; ni < 4; ++ni) {
                    const int ch = ni * 16 + fr;
                    const int tk = mi * 16 + sl * 4;
#pragma unroll
                    for (int r = 0; r < 4; ++r)
                        piece[(tk + r) * 68 + ch] = f2bf(acc[mi][ni][r]);
                }
            __syncthreads();
#pragma unroll
            for (int i = 0; i < 32; ++i) {
                const int chunk = i * 512 + tid;
                const int row = chunk >> 4, c8 = chunk & 15;
                const int p = row >> 7, tk = row & 127;
                const int wrp = p >> 2, wcp = p & 3;
                const uint2 v = *(const uint2*)(sm + p * 8704 + tk * 68 + c8 * 4);
                *(uint2*)(v_tm + ((b * 4096 + tok0 + wrp * 128 + tk) * 1024L + (n0 - 2048) + wcp * 64 + c8 * 4)) = v;
            }
        }
    } else {
        float bi[4];
#pragma unroll
        for (int ni = 0; ni < 4; ++ni) bi[ni] = bias[n0 + wc * 64 + ni * 16 + fr];
#pragma unroll
        for (int pass = 0; pass < 2; ++pass) {
            float* pieceF = (float*)smem4 + wid * 4352;
            if (pass) __syncthreads();
#pragma unroll
            for (int mi2 = 0; mi2 < 4; ++mi2) {
                const int mi = pass * 4 + mi2;
#pragma unroll
                for (int ni = 0; ni < 4; ++ni) {
                    const int ch = ni * 16 + fr;
                    const int tk = mi2 * 16 + sl * 4;
#pragma unroll
                    for (int r = 0; r < 4; ++r)
                        pieceF[(tk + r) * 68 + ch] = acc[mi][ni][r] + bi[ni];
                }
            }
            __syncthreads();
#pragma unroll
            for (int i = 0; i < 16; ++i) {
                const int chunk = i * 512 + tid;
                const int row = chunk >> 4, c4 = chunk & 15;
                const int p = row >> 6, tk = row & 63;
                const int wrp = p >> 2, wcp = p & 3;
                const float4 v = *(const float4*)((float*)smem4 + p * 4352 + tk * 68 + c4 * 4);
                *(float4*)(outp + (m0 + wrp * 128 + pass * 64 + tk) * 1024L + n0 + wcp * 64 + c4 * 4) = v;
            }
        }
    }
}

// ---------------- partial Gram + partial square-sums per (b,h,seg) ----------------
__global__ __launch_bounds__(512, 2) void k_gram(
    const u16* __restrict__ qkT, float* __restrict__ gram_part, float* __restrict__ sq_part)
{
    __shared__ u16 lQ[64 * 256];
    __shared__ u16 lK[64 * 256];

    const int blk = blockIdx.x;
    const int seg = blk & 15;
    const int bh = blk >> 4;
    const int b = bh >> 4, h = bh & 15;
    const int tid = threadIdx.x;
    const int wid = tid >> 6, lane = tid & 63;

    {
        const int r2 = lane >> 5;
        const int slot = lane & 31;
        const int rbase = wid * 8;
#pragma unroll
        for (int i = 0; i < 4; ++i) {
            const int r = rbase + i * 2 + r2;
            const int col = seg * 256 + ((slot ^ (r & 7)) << 3);
            const u16* gq = qkT + ((long)(b * 2048 + h * 64 + r)) * 4096 + col;
            const u16* gk = qkT + ((long)(b * 2048 + 1024 + h * 64 + r)) * 4096 + col;
            __builtin_amdgcn_global_load_lds((gp_t)gq, (lp_t)(lQ + (rbase + i * 2) * 256), 16, 0, 0);
            __builtin_amdgcn_global_load_lds((gp_t)gk, (lp_t)(lK + (rbase + i * 2) * 256), 16, 0, 0);
        }
    }
    __syncthreads();

    {
        const int row = tid >> 2, q4 = tid & 3;
        const u16* src = (row < 64 ? lQ + row * 256 : lK + (row - 64) * 256) + q4 * 64;
        float s = 0.f;
#pragma unroll
        for (int i = 0; i < 8; ++i) {
            uint4 v = *(const uint4*)(src + i * 8);
            float a0, a1;
            a0 = bf2f((u16)(v.x & 0xFFFF)); a1 = bf2f((u16)(v.x >> 16)); s += a0 * a0 + a1 * a1;
            a0 = bf2f((u16)(v.y & 0xFFFF)); a1 = bf2f((u16)(v.y >> 16)); s += a0 * a0 + a1 * a1;
            a0 = bf2f((u16)(v.z & 0xFFFF)); a1 = bf2f((u16)(v.z >> 16)); s += a0 * a0 + a1 * a1;
            a0 = bf2f((u16)(v.w & 0xFFFF)); a1 = bf2f((u16)(v.w >> 16)); s += a0 * a0 + a1 * a1;
        }
        s += __shfl_xor(s, 1);
        s += __shfl_xor(s, 2);
        if (q4 == 0) sq_part[(long)blk * 128 + row] = s;
    }

    const int mrow = wid >> 1, npair = wid & 1;
    const int fr = lane & 15, sl = lane >> 4;
    f32x4 acc[2];
    acc[0] = (f32x4){0.f, 0.f, 0.f, 0.f};
    acc[1] = (f32x4){0.f, 0.f, 0.f, 0.f};
#pragma unroll
    for (int ks = 0; ks < 8; ++ks) {
        const int ra = mrow * 16 + fr;
        const bf16x8 a = *(const bf16x8*)(lQ + ra * 256 + (((ks * 4 + sl) ^ (ra & 7)) << 3));
#pragma unroll
        for (int ni = 0; ni < 2; ++ni) {
            const int rb = npair * 32 + ni * 16 + fr;
            const bf16x8 bb = *(const bf16x8*)(lK + rb * 256 + (((ks * 4 + sl) ^ (rb & 7)) << 3));
            acc[ni] = __builtin_amdgcn_mfma_f32_16x16x32_bf16(a, bb, acc[ni], 0, 0, 0);
        }
    }
    float* gp = gram_part + (long)blk * 4096;
#pragma unroll
    for (int ni = 0; ni < 2; ++ni)
#pragma unroll
        for (int r = 0; r < 4; ++r)
            gp[(mrow * 16 + sl * 4 + r) * 64 + npair * 32 + ni * 16 + fr] = acc[ni][r];
}

// ---------------- reduce partials + normalize + softmax -> attn bf16 ----------------
__global__ __launch_bounds__(256) void k_smax(
    const float* __restrict__ gram_part, const float* __restrict__ sq_part,
    const float* __restrict__ temperature, u16* __restrict__ attn_g)
{
    const int row = blockIdx.x * 4 + (threadIdx.x >> 6);
    const int e = threadIdx.x & 63;
    const int bh = row >> 6, d = row & 63;
    const int h = bh & 15;
    float raw = 0.f, sqq = 0.f, sqk = 0.f;
    const float* gp = gram_part + (long)bh * 16 * 4096 + d * 64 + e;
    const float* sp = sq_part + (long)bh * 16 * 128;
#pragma unroll
    for (int s = 0; s < 16; ++s) {
        raw += gp[s * 4096];
        sqq += sp[s * 128 + d];
        sqk += sp[s * 128 + 64 + e];
    }
    const float rq = 1.f / fmaxf(sqrtf(sqq), 1e-12f);
    const float rk = 1.f / fmaxf(sqrtf(sqk), 1e-12f);
    const float v = raw * rq * rk * temperature[h];
    float mx = v;
#pragma unroll
    for (int o = 32; o; o >>= 1) mx = fmaxf(mx, __shfl_xor(mx, o));
    const float p = __expf(v - mx);
    float sum = p;
#pragma unroll
    for (int o = 32; o; o >>= 1) sum += __shfl_xor(sum, o);
    attn_g[(long)row * 64 + e] = f2bf(p / sum);
}

// ---------------- PV: y[b, n, h*64+d] = sum_e attn[d][e] * v[e][n] ----------------
__global__ __launch_bounds__(256) void k_pv(
    const u16* __restrict__ attn_g, const u16* __restrict__ v_tm,
    u16* __restrict__ y)
{
    __shared__ u16 lP[64 * 72];
    __shared__ u16 lV[128 * 64];
    __shared__ u16 lY[128 * 72];

    const int blk = blockIdx.x;
    const int seg = blk & 15, bh = blk >> 4;
    const int b = bh >> 4, h = bh & 15;
    const int tid = threadIdx.x;
    const int wid = tid >> 6, lane = tid & 63;
    const int wr = wid >> 1, wc = wid & 1;
    const int fr = lane & 15;

    {
        const int d = tid >> 2, part = tid & 3;
        const u16* g = attn_g + ((long)bh * 64 + d) * 64 + part * 16;
        u16* l = lP + d * 72 + part * 16;
        *(uint4*)(l) = *(const uint4*)(g);
        *(uint4*)(l + 8) = *(const uint4*)(g + 8);
    }

    for (int cn = 0; cn < 2; ++cn) {
        const int tok0 = seg * 256 + cn * 128;
        __syncthreads();
#pragma unroll
        for (int i = 0; i < 4; ++i) {
            const int cc = wid * 4 + i;
            const int row = cc * 8 + (lane >> 3);
            const int slot = lane & 7;
            const u16* g = v_tm + ((long)(b * 4096 + tok0 + row)) * 1024 + h * 64 + ((slot ^ (row & 7)) << 3);
            __builtin_amdgcn_global_load_lds((gp_t)g, (lp_t)(lV + cc * 512), 16, 0, 0);
        }
        __syncthreads();
        f32x4 acc[2][4];
#pragma unroll
        for (int i = 0; i < 2; ++i)
#pragma unroll
            for (int j = 0; j < 4; ++j) acc[i][j] = (f32x4){0.f, 0.f, 0.f, 0.f};
#pragma unroll
        for (int s = 0; s < 2; ++s) {
            bf16x8 ap[2];
#pragma unroll
            for (int mi = 0; mi < 2; ++mi) {
                const int d = wr * 32 + mi * 16 + fr;
                ap[mi] = *(const bf16x8*)(lP + d * 72 + s * 32 + ((lane >> 4) << 3));
            }
#pragma unroll
            for (int ni = 0; ni < 4; ++ni) {
                const int tr = wc * 64 + ni * 16 + fr;
                const bf16x8 bv = *(const bf16x8*)(lV + tr * 64 + (((s * 4 + (lane >> 4)) ^ (tr & 7)) << 3));
#pragma unroll
                for (int mi = 0; mi < 2; ++mi)
                    acc[mi][ni] = __builtin_amdgcn_mfma_f32_16x16x32_bf16(ap[mi], bv, acc[mi][ni], 0, 0, 0);
            }
        }
#pragma unroll
        for (int mi = 0; mi < 2; ++mi)
#pragma unroll
            for (int ni = 0; ni < 4; ++ni) {
                const int tk = wc * 64 + ni * 16 + fr;
                const int d0 = wr * 32 + mi * 16 + ((lane >> 4) << 2);
                ushort4 w;
                w.x = f2bf(acc[mi][ni][0]); w.y = f2bf(acc[mi][ni][1]);
                w.z = f2bf(acc[mi][ni][2]); w.w = f2bf(acc[mi][ni][3]);
                *(ushort4*)(lY + tk * 72 + d0) = w;
            }
        __syncthreads();
        {
            const int tk = tid >> 1, half = tid & 1;
            const u16* sp = lY + tk * 72 + half * 32;
            u16* dp = y + ((long)(b * 4096 + tok0 + tk)) * 1024 + h * 64 + half * 32;
#pragma unroll
            for (int i = 0; i < 4; ++i)
                ((uint4*)dp)[i] = ((const uint4*)sp)[i];
        }
    }
}

// ---------------- launch ----------------
extern "C" void kernel_launch(void* const* d_in, const int* in_sizes, int n_in,
                              void* d_out, int out_size, void* d_ws, size_t ws_size,
                              hipStream_t stream) {
    const float* x = (const float*)d_in[0];
    const float* w_qkv = (const float*)d_in[1];
    const float* temperature = (const float*)d_in[2];
    const float* w_proj = (const float*)d_in[3];
    const float* b_proj = (const float*)d_in[4];
    float* out = (float*)d_out;
    char* ws = (char*)d_ws;

    u16* wqT   = (u16*)(ws);                       //   6,291,456 B  [3072][1024] bf16
    u16* wpT   = (u16*)(ws + 6291456);             //   2,097,152 B  [1024][1024] bf16
    u16* xb    = (u16*)(ws + 8388608);             //  67,108,864 B  [32768][1024] bf16
    u16* qkT   = (u16*)(ws + 75497472);            // 134,217,728 B  [8][2048][4096] bf16
    u16* v_tm  = (u16*)(ws + 209715200);           //  67,108,864 B  [8][4096][1024] bf16
    u16* attn_g = (u16*)(ws + 276889600);          //   1,048,576 B  [128][64][64] bf16
    float* gram_part = (float*)(ws + 8388608);     //  33,554,432 B  [2048][64][64] f32 (xb overlay)
    float* sq_part   = (float*)(ws + 41943040);    //   1,048,576 B  [2048][128] f32
    u16* y = xb;                                   // alias: written by k_pv after k_smax

    k_pack_x<<<2048, 256, 0, stream>>>(x, xb, 8388608);
    k_transpose_w<<<768, 256, 0, stream>>>(w_qkv, wqT, 3072);
    k_transpose_w<<<256, 256, 0, stream>>>(w_proj, wpT, 1024);
    k_gemm<0><<<1536, 512, 0, stream>>>(xb, wqT, 12, qkT, v_tm, nullptr, nullptr);
    k_gram<<<2048, 512, 0, stream>>>(qkT, gram_part, sq_part);
    k_smax<<<2048, 256, 0, stream>>>(gram_part, sq_part, temperature, attn_g);
    k_pv<<<2048, 256, 0, stream>>>(attn_g, v_tm, y);
    k_gemm<1><<<512, 512, 0, stream>>>(y, wpT, 4, nullptr, nullptr, out, b_proj);
}

// Round 6
// 392.059 us; speedup vs baseline: 1.0626x; 1.0626x over previous
//
#include <hip/hip_runtime.h>
#include <cstdint>

typedef unsigned short u16;
typedef unsigned int u32;
typedef __attribute__((ext_vector_type(8))) short bf16x8;
typedef __attribute__((ext_vector_type(4))) float f32x4;

typedef const u32 __attribute__((address_space(1)))* gp_t;
typedef u32 __attribute__((address_space(3)))* lp_t;

__device__ __forceinline__ u16 f2bf(float f) {
    union { float f; u32 u; } v; v.f = f;
    u32 r = v.u + 0x7FFFu + ((v.u >> 16) & 1u);   // RNE
    return (u16)(r >> 16);
}
__device__ __forceinline__ float bf2f(u16 h) {
    union { u32 u; float f; } v; v.u = ((u32)h) << 16;
    return v.f;
}

// ---------------- pack x (fp32 -> bf16), vectorized ----------------
__global__ void k_pack_x(const float* __restrict__ x, u16* __restrict__ xb, int n4) {
    int stride = gridDim.x * blockDim.x;
    for (int i = blockIdx.x * blockDim.x + threadIdx.x; i < n4; i += stride) {
        float4 v = ((const float4*)x)[i];
        ushort4 o;
        o.x = f2bf(v.x); o.y = f2bf(v.y); o.z = f2bf(v.z); o.w = f2bf(v.w);
        ((ushort4*)xb)[i] = o;
    }
}

// ---------------- transpose weight [1024][ncols] f32 -> [ncols][1024] bf16 ----
__global__ void k_transpose_w(const float* __restrict__ src, u16* __restrict__ dst, int ncols) {
    __shared__ float t[64][65];
    int ntn = ncols >> 6;
    int kb = (blockIdx.x / ntn) * 64;
    int nb = (blockIdx.x % ntn) * 64;
    for (int i = threadIdx.x; i < 4096; i += 256) {
        int r = i >> 6, c = i & 63;
        t[r][c] = src[(long)(kb + r) * ncols + nb + c];
    }
    __syncthreads();
    for (int i = threadIdx.x; i < 4096; i += 256) {
        int r = i >> 6, c = i & 63;
        dst[(long)(nb + r) * 1024 + kb + c] = f2bf(t[c][r]);
    }
}

// ---------------- 256x256 GEMM, BK=64, 4-phase/K-tile, reads pipelined 1 phase ----
// EPI 0: qkv epilogue, A=[32768][1024], Bt=[3072][1024], grid 1536
// EPI 1: proj epilogue, A=v_tm [8*4096][1024], Bt = wmix batched [8][1024][1024], grid 512
template<int EPI>
__global__ __launch_bounds__(512, 2) void k_gemm(
    const u16* __restrict__ A, const u16* __restrict__ Bt,
    int nTilesN,
    u16* __restrict__ qkT, u16* __restrict__ v_tm,
    float* __restrict__ outp, const float* __restrict__ bias)
{
    __shared__ uint4 smem4[8704];            // 139264 B (main loop uses first 128 KiB)
    u16* sm = (u16*)smem4;

    const int tid = threadIdx.x;
    const int wid = tid >> 6, lane = tid & 63;
    const int wr = wid >> 2, wc = wid & 3;   // 2M x 4N waves
    const int fr = lane & 15, sl = lane >> 4;

    const int nwg = gridDim.x;
    const int cpx = nwg >> 3;
    const int logical = (blockIdx.x & 7) * cpx + (blockIdx.x >> 3);

    long m0; int n0;
    const u16* BtEff = Bt;
    if (EPI == 0) {
        const int bn = logical % nTilesN;
        m0 = (long)(logical / nTilesN) * 256;
        n0 = bn * 256;
    } else {
        const int b = logical >> 6;
        const int mt = (logical >> 2) & 15;
        const int nt = logical & 3;
        m0 = (long)b * 4096 + mt * 256;
        n0 = nt * 256;
        BtEff = Bt + ((long)b << 20);        // per-batch 1024*1024
    }

    // staging geometry: per stage-call a wave writes 2x1KB linear chunks (16 rows x 64B)
    const int srow = wid * 32 + (lane >> 2);
    const int kswz = (((lane & 3) ^ ((srow >> 1) & 3)) << 3);
    const u16* gA = A + (m0 + srow) * 1024L + kswz;
    const u16* gB = BtEff + ((long)n0 + srow) * 1024L + kswz;
    const int ldst = wid * 1024;

    // frag-read geometry (XOR slot is row-invariant per lane)
    const int fxor = ((sl ^ ((fr >> 1) & 3)) << 3);
    const int aBase = (wr * 128 + fr) * 32 + fxor;      // + mi*512 + d*16384 + ks*8192
    const int bBase = 32768 + (wc * 64 + fr) * 32 + fxor;

    f32x4 acc[8][4];
#pragma unroll
    for (int i = 0; i < 8; ++i)
#pragma unroll
        for (int j = 0; j < 4; ++j) acc[i][j] = (f32x4){0.f, 0.f, 0.f, 0.f};

#define STAGE_A(d, kh, ts) do { \
    const u16* g_ = gA + (ts) * 64 + (kh) * 32; \
    u16* l_ = sm + (d) * 16384 + (kh) * 8192 + ldst; \
    __builtin_amdgcn_global_load_lds((gp_t)g_, (lp_t)l_, 16, 0, 0); \
    __builtin_amdgcn_global_load_lds((gp_t)(g_ + 16 * 1024), (lp_t)(l_ + 512), 16, 0, 0); \
} while (0)
#define STAGE_B(d, kh, ts) do { \
    const u16* g_ = gB + (ts) * 64 + (kh) * 32; \
    u16* l_ = sm + 32768 + (d) * 16384 + (kh) * 8192 + ldst; \
    __builtin_amdgcn_global_load_lds((gp_t)g_, (lp_t)l_, 16, 0, 0); \
    __builtin_amdgcn_global_load_lds((gp_t)(g_ + 16 * 1024), (lp_t)(l_ + 512), 16, 0, 0); \
} while (0)

    // prologue: T0.A.kh0, T0.B.kh0, T0.A.kh1, T0.B.kh1, T1.A.kh0, T1.B.kh0
    STAGE_A(0, 0, 0); STAGE_B(0, 0, 0);
    STAGE_A(0, 1, 0); STAGE_B(0, 1, 0);
    STAGE_A(1, 0, 1); STAGE_B(1, 0, 1);
    asm volatile("s_waitcnt vmcnt(8)" ::: "memory");   // T0.kh0 (A,B) landed
    __builtin_amdgcn_s_barrier();

    bf16x8 afX[4], afY[4], bfX[4], bfY[4];
    // prologue frag reads: T0 kh0 (consumed by P1 of T=0)
#pragma unroll
    for (int ni = 0; ni < 4; ++ni) bfX[ni] = *(const bf16x8*)(sm + bBase + ni * 512);
#pragma unroll
    for (int mi = 0; mi < 4; ++mi) afX[mi] = *(const bf16x8*)(sm + aBase + mi * 512);

#pragma unroll 2
    for (int T = 0; T < 16; ++T) {
        const int d = T & 1;
        const int t1 = (T + 1 < 16) ? T + 1 : 15;
        const int t2 = (T + 2 < 16) ? T + 2 : 15;
        const int base = d * 16384;
        const int nbase = (d ^ 1) * 16384;

        // ---- P1: MFMA(mh0,ks0); read mh1/ks0; vmcnt(6) covers T.kh1 for P2 reads ----
#pragma unroll
        for (int mi = 0; mi < 4; ++mi)
            afY[mi] = *(const bf16x8*)(sm + aBase + (4 + mi) * 512 + base);
        STAGE_A(d ^ 1, 1, t1);                          // (T+1).A.kh1
        asm volatile("s_waitcnt vmcnt(6)" ::: "memory");
        __builtin_amdgcn_s_barrier();
        __builtin_amdgcn_s_setprio(1);
#pragma unroll
        for (int mi = 0; mi < 4; ++mi)
#pragma unroll
            for (int ni = 0; ni < 4; ++ni)
                acc[mi][ni] = __builtin_amdgcn_mfma_f32_16x16x32_bf16(afX[mi], bfX[ni], acc[mi][ni], 0, 0, 0);
        __builtin_amdgcn_s_setprio(0);
        __builtin_amdgcn_s_barrier();

        // ---- P2: MFMA(mh1,ks0); read ks1 (bfY) + mh0/ks1 (afX) ----
#pragma unroll
        for (int ni = 0; ni < 4; ++ni)
            bfY[ni] = *(const bf16x8*)(sm + bBase + ni * 512 + base + 8192);
#pragma unroll
        for (int mi = 0; mi < 4; ++mi)
            afX[mi] = *(const bf16x8*)(sm + aBase + mi * 512 + base + 8192);
        STAGE_B(d ^ 1, 1, t1);                          // (T+1).B.kh1
        __builtin_amdgcn_s_barrier();
        __builtin_amdgcn_s_setprio(1);
#pragma unroll
        for (int mi = 0; mi < 4; ++mi)
#pragma unroll
            for (int ni = 0; ni < 4; ++ni)
                acc[mi + 4][ni] = __builtin_amdgcn_mfma_f32_16x16x32_bf16(afY[mi], bfX[ni], acc[mi + 4][ni], 0, 0, 0);
        __builtin_amdgcn_s_setprio(0);
        __builtin_amdgcn_s_barrier();

        // ---- P3: MFMA(mh0,ks1); read mh1/ks1; vmcnt(6) covers (T+1).kh0 for P4 reads ----
#pragma unroll
        for (int mi = 0; mi < 4; ++mi)
            afY[mi] = *(const bf16x8*)(sm + aBase + (4 + mi) * 512 + base + 8192);
        STAGE_A(d, 0, t2);                              // (T+2).A.kh0
        asm volatile("s_waitcnt vmcnt(6)" ::: "memory");
        __builtin_amdgcn_s_barrier();
        __builtin_amdgcn_s_setprio(1);
#pragma unroll
        for (int mi = 0; mi < 4; ++mi)
#pragma unroll
            for (int ni = 0; ni < 4; ++ni)
                acc[mi][ni] = __builtin_amdgcn_mfma_f32_16x16x32_bf16(afX[mi], bfY[ni], acc[mi][ni], 0, 0, 0);
        __builtin_amdgcn_s_setprio(0);
        __builtin_amdgcn_s_barrier();

        // ---- P4: MFMA(mh1,ks1); read (T+1) kh0 frags (bfX, afX) from other buffer ----
#pragma unroll
        for (int ni = 0; ni < 4; ++ni)
            bfX[ni] = *(const bf16x8*)(sm + bBase + ni * 512 + nbase);
#pragma unroll
        for (int mi = 0; mi < 4; ++mi)
            afX[mi] = *(const bf16x8*)(sm + aBase + mi * 512 + nbase);
        STAGE_B(d, 0, t2);                              // (T+2).B.kh0
        __builtin_amdgcn_s_barrier();
        __builtin_amdgcn_s_setprio(1);
#pragma unroll
        for (int mi = 0; mi < 4; ++mi)
#pragma unroll
            for (int ni = 0; ni < 4; ++ni)
                acc[mi + 4][ni] = __builtin_amdgcn_mfma_f32_16x16x32_bf16(afY[mi], bfY[ni], acc[mi + 4][ni], 0, 0, 0);
        __builtin_amdgcn_s_setprio(0);
        __builtin_amdgcn_s_barrier();
    }
#undef STAGE_A
#undef STAGE_B
    asm volatile("s_waitcnt vmcnt(0)" ::: "memory");   // drain tail junk stages
    __syncthreads();

    if (EPI == 0) {
        const long b = m0 >> 12;
        const int tok0 = (int)(m0 & 4095);
        if (n0 < 2048) {
            u16* piece = sm + wid * 8704;
#pragma unroll
            for (int mi = 0; mi < 8; ++mi)
#pragma unroll
                for (int ni = 0; ni < 4; ++ni) {
                    const int ch = ni * 16 + fr;
                    const int tk = mi * 16 + sl * 4;
                    ushort4 w;
                    w.x = f2bf(acc[mi][ni][0]); w.y = f2bf(acc[mi][ni][1]);
                    w.z = f2bf(acc[mi][ni][2]); w.w = f2bf(acc[mi][ni][3]);
                    *(ushort4*)(piece + ch * 136 + tk) = w;
                }
            __syncthreads();
#pragma unroll
            for (int i = 0; i < 16; ++i) {
                const int chunk = i * 512 + tid;
                const int row = chunk >> 4, c16 = chunk & 15;
                const int p = row >> 6, chl = row & 63;
                const int wrp = p >> 2, wcp = p & 3;
                const uint4 v = *(const uint4*)(sm + p * 8704 + chl * 136 + c16 * 8);
                *(uint4*)(qkT + ((b * 2048 + n0 + wcp * 64 + chl) * 4096L + tok0 + wrp * 128 + c16 * 8)) = v;
            }
        } else {
            u16* piece = sm + wid * 8704;
#pragma unroll
            for (int mi = 0; mi < 8; ++mi)
#pragma unroll
                for (int ni = 0; ni < 4; ++ni) {
                    const int ch = ni * 16 + fr;
                    const int tk = mi * 16 + sl * 4;
#pragma unroll
                    for (int r = 0; r < 4; ++r)
                        piece[(tk + r) * 68 + ch] = f2bf(acc[mi][ni][r]);
                }
            __syncthreads();
#pragma unroll
            for (int i = 0; i < 32; ++i) {
                const int chunk = i * 512 + tid;
                const int row = chunk >> 4, c8 = chunk & 15;
                const int p = row >> 7, tk = row & 127;
                const int wrp = p >> 2, wcp = p & 3;
                const uint2 v = *(const uint2*)(sm + p * 8704 + tk * 68 + c8 * 4);
                *(uint2*)(v_tm + ((b * 4096 + tok0 + wrp * 128 + tk) * 1024L + (n0 - 2048) + wcp * 64 + c8 * 4)) = v;
            }
        }
    } else {
        float bi[4];
#pragma unroll
        for (int ni = 0; ni < 4; ++ni) bi[ni] = bias[n0 + wc * 64 + ni * 16 + fr];
#pragma unroll
        for (int pass = 0; pass < 2; ++pass) {
            float* pieceF = (float*)smem4 + wid * 4352;
            if (pass) __syncthreads();
#pragma unroll
            for (int mi2 = 0; mi2 < 4; ++mi2) {
                const int mi = pass * 4 + mi2;
#pragma unroll
                for (int ni = 0; ni < 4; ++ni) {
                    const int ch = ni * 16 + fr;
                    const int tk = mi2 * 16 + sl * 4;
#pragma unroll
                    for (int r = 0; r < 4; ++r)
                        pieceF[(tk + r) * 68 + ch] = acc[mi][ni][r] + bi[ni];
                }
            }
            __syncthreads();
#pragma unroll
            for (int i = 0; i < 16; ++i) {
                const int chunk = i * 512 + tid;
                const int row = chunk >> 4, c4 = chunk & 15;
                const int p = row >> 6, tk = row & 63;
                const int wrp = p >> 2, wcp = p & 3;
                const float4 v = *(const float4*)((float*)smem4 + p * 4352 + tk * 68 + c4 * 4);
                *(float4*)(outp + (m0 + wrp * 128 + pass * 64 + tk) * 1024L + n0 + wcp * 64 + c4 * 4) = v;
            }
        }
    }
}

// ---------------- partial Gram + partial square-sums per (b,h,seg) ----------------
__global__ __launch_bounds__(512, 2) void k_gram(
    const u16* __restrict__ qkT, float* __restrict__ gram_part, float* __restrict__ sq_part)
{
    __shared__ u16 lQ[64 * 256];
    __shared__ u16 lK[64 * 256];

    const int blk = blockIdx.x;
    const int seg = blk & 15;
    const int bh = blk >> 4;
    const int b = bh >> 4, h = bh & 15;
    const int tid = threadIdx.x;
    const int wid = tid >> 6, lane = tid & 63;

    {
        const int r2 = lane >> 5;
        const int slot = lane & 31;
        const int rbase = wid * 8;
#pragma unroll
        for (int i = 0; i < 4; ++i) {
            const int r = rbase + i * 2 + r2;
            const int col = seg * 256 + ((slot ^ (r & 7)) << 3);
            const u16* gq = qkT + ((long)(b * 2048 + h * 64 + r)) * 4096 + col;
            const u16* gk = qkT + ((long)(b * 2048 + 1024 + h * 64 + r)) * 4096 + col;
            __builtin_amdgcn_global_load_lds((gp_t)gq, (lp_t)(lQ + (rbase + i * 2) * 256), 16, 0, 0);
            __builtin_amdgcn_global_load_lds((gp_t)gk, (lp_t)(lK + (rbase + i * 2) * 256), 16, 0, 0);
        }
    }
    __syncthreads();

    {
        const int row = tid >> 2, q4 = tid & 3;
        const u16* src = (row < 64 ? lQ + row * 256 : lK + (row - 64) * 256) + q4 * 64;
        float s = 0.f;
#pragma unroll
        for (int i = 0; i < 8; ++i) {
            uint4 v = *(const uint4*)(src + i * 8);
            float a0, a1;
            a0 = bf2f((u16)(v.x & 0xFFFF)); a1 = bf2f((u16)(v.x >> 16)); s += a0 * a0 + a1 * a1;
            a0 = bf2f((u16)(v.y & 0xFFFF)); a1 = bf2f((u16)(v.y >> 16)); s += a0 * a0 + a1 * a1;
            a0 = bf2f((u16)(v.z & 0xFFFF)); a1 = bf2f((u16)(v.z >> 16)); s += a0 * a0 + a1 * a1;
            a0 = bf2f((u16)(v.w & 0xFFFF)); a1 = bf2f((u16)(v.w >> 16)); s += a0 * a0 + a1 * a1;
        }
        s += __shfl_xor(s, 1);
        s += __shfl_xor(s, 2);
        if (q4 == 0) sq_part[(long)blk * 128 + row] = s;
    }

    const int mrow = wid >> 1, npair = wid & 1;
    const int fr = lane & 15, sl = lane >> 4;
    f32x4 acc[2];
    acc[0] = (f32x4){0.f, 0.f, 0.f, 0.f};
    acc[1] = (f32x4){0.f, 0.f, 0.f, 0.f};
#pragma unroll
    for (int ks = 0; ks < 8; ++ks) {
        const int ra = mrow * 16 + fr;
        const bf16x8 a = *(const bf16x8*)(lQ + ra * 256 + (((ks * 4 + sl) ^ (ra & 7)) << 3));
#pragma unroll
        for (int ni = 0; ni < 2; ++ni) {
            const int rb = npair * 32 + ni * 16 + fr;
            const bf16x8 bb = *(const bf16x8*)(lK + rb * 256 + (((ks * 4 + sl) ^ (rb & 7)) << 3));
            acc[ni] = __builtin_amdgcn_mfma_f32_16x16x32_bf16(a, bb, acc[ni], 0, 0, 0);
        }
    }
    float* gp = gram_part + (long)blk * 4096;
#pragma unroll
    for (int ni = 0; ni < 2; ++ni)
#pragma unroll
        for (int r = 0; r < 4; ++r)
            gp[(mrow * 16 + sl * 4 + r) * 64 + npair * 32 + ni * 16 + fr] = acc[ni][r];
}

// ---------------- reduce partials + normalize + softmax -> attn bf16 ----------------
__global__ __launch_bounds__(256) void k_smax(
    const float* __restrict__ gram_part, const float* __restrict__ sq_part,
    const float* __restrict__ temperature, u16* __restrict__ attn_g)
{
    const int row = blockIdx.x * 4 + (threadIdx.x >> 6);
    const int e = threadIdx.x & 63;
    const int bh = row >> 6, d = row & 63;
    const int h = bh & 15;
    float raw = 0.f, sqq = 0.f, sqk = 0.f;
    const float* gp = gram_part + (long)bh * 16 * 4096 + d * 64 + e;
    const float* sp = sq_part + (long)bh * 16 * 128;
#pragma unroll
    for (int s = 0; s < 16; ++s) {
        raw += gp[s * 4096];
        sqq += sp[s * 128 + d];
        sqk += sp[s * 128 + 64 + e];
    }
    const float rq = 1.f / fmaxf(sqrtf(sqq), 1e-12f);
    const float rk = 1.f / fmaxf(sqrtf(sqk), 1e-12f);
    const float v = raw * rq * rk * temperature[h];
    float mx = v;
#pragma unroll
    for (int o = 32; o; o >>= 1) mx = fmaxf(mx, __shfl_xor(mx, o));
    const float p = __expf(v - mx);
    float sum = p;
#pragma unroll
    for (int o = 32; o; o >>= 1) sum += __shfl_xor(sum, o);
    attn_g[(long)row * 64 + e] = f2bf(p / sum);
}

// ---------------- fold attn into w_proj: wmix[b][cout][h*64+e] = sum_d attn[bh][d][e] wpT[cout][h*64+d]
// grid: bh*4 + nseg (512 blocks), 256 threads
__global__ __launch_bounds__(256) void k_wmix(
    const u16* __restrict__ attn_g, const u16* __restrict__ wpT, u16* __restrict__ wmix)
{
    __shared__ u16 lA[64 * 72];     // attnT [e][d] pitch 72
    __shared__ u16 lB[256 * 64];    // wpT panel [cout r][d 64], swizzled

    const int blk = blockIdx.x;
    const int nseg = blk & 3, bh = blk >> 2;
    const int b = bh >> 4, h = bh & 15;
    const int tid = threadIdx.x;
    const int wid = tid >> 6, lane = tid & 63;
    const int fr = lane & 15, sl = lane >> 4;

    // stage wpT panel: 256 rows x 128B via global_load_lds (32 chunks x 8 rows)
#pragma unroll
    for (int i = 0; i < 8; ++i) {
        const int cc = wid * 8 + i;
        const int row = cc * 8 + (lane >> 3);
        const int slot = lane & 7;
        const u16* g = wpT + (long)(nseg * 256 + row) * 1024 + h * 64 + ((slot ^ (row & 7)) << 3);
        __builtin_amdgcn_global_load_lds((gp_t)g, (lp_t)(lB + cc * 512), 16, 0, 0);
    }
    // stage attn transposed: lA[e*72+d] = attn[d][e]
    {
        const u16* src = attn_g + (long)bh * 4096;
        for (int i = tid; i < 4096; i += 256) {
            const int d = i >> 6, e = i & 63;
            lA[e * 72 + d] = src[i];
        }
    }
    __syncthreads();

    f32x4 acc[4][4];
#pragma unroll
    for (int i = 0; i < 4; ++i)
#pragma unroll
        for (int j = 0; j < 4; ++j) acc[i][j] = (f32x4){0.f, 0.f, 0.f, 0.f};

#pragma unroll
    for (int ks = 0; ks < 2; ++ks) {
        bf16x8 a[4], bb[4];
#pragma unroll
        for (int mi = 0; mi < 4; ++mi)
            a[mi] = *(const bf16x8*)(lA + (mi * 16 + fr) * 72 + ks * 32 + sl * 8);
#pragma unroll
        for (int ni = 0; ni < 4; ++ni) {
            const int rb = wid * 64 + ni * 16 + fr;
            bb[ni] = *(const bf16x8*)(lB + rb * 64 + (((ks * 4 + sl) ^ (rb & 7)) << 3));
        }
#pragma unroll
        for (int mi = 0; mi < 4; ++mi)
#pragma unroll
            for (int ni = 0; ni < 4; ++ni)
                acc[mi][ni] = __builtin_amdgcn_mfma_f32_16x16x32_bf16(a[mi], bb[ni], acc[mi][ni], 0, 0, 0);
    }

    u16* dst = wmix + ((long)b << 20);
#pragma unroll
    for (int mi = 0; mi < 4; ++mi)
#pragma unroll
        for (int ni = 0; ni < 4; ++ni) {
            const int cout = nseg * 256 + wid * 64 + ni * 16 + fr;
            const int e0 = mi * 16 + sl * 4;
            ushort4 w;
            w.x = f2bf(acc[mi][ni][0]); w.y = f2bf(acc[mi][ni][1]);
            w.z = f2bf(acc[mi][ni][2]); w.w = f2bf(acc[mi][ni][3]);
            *(ushort4*)(dst + (long)cout * 1024 + h * 64 + e0) = w;
        }
}

// ---------------- launch ----------------
extern "C" void kernel_launch(void* const* d_in, const int* in_sizes, int n_in,
                              void* d_out, int out_size, void* d_ws, size_t ws_size,
                              hipStream_t stream) {
    const float* x = (const float*)d_in[0];
    const float* w_qkv = (const float*)d_in[1];
    const float* temperature = (const float*)d_in[2];
    const float* w_proj = (const float*)d_in[3];
    const float* b_proj = (const float*)d_in[4];
    float* out = (float*)d_out;
    char* ws = (char*)d_ws;

    u16* wqT   = (u16*)(ws);                       //   6,291,456 B  [3072][1024] bf16
    u16* wpT   = (u16*)(ws + 6291456);             //   2,097,152 B  [1024][1024] bf16
    u16* xb    = (u16*)(ws + 8388608);             //  67,108,864 B  [32768][1024] bf16
    u16* qkT   = (u16*)(ws + 75497472);            // 134,217,728 B  [8][2048][4096] bf16
    u16* v_tm  = (u16*)(ws + 209715200);           //  67,108,864 B  [8][4096][1024] bf16
    u16* attn_g = (u16*)(ws + 276889600);          //   1,048,576 B  [128][64][64] bf16
    float* gram_part = (float*)(ws + 8388608);     //  33,554,432 B  [2048][64][64] f32 (xb overlay)
    float* sq_part   = (float*)(ws + 41943040);    //   1,048,576 B  [2048][128] f32
    u16* wmix = (u16*)(ws + 8388608);              //  16,777,216 B  [8][1024][1024] bf16 (gram overlay, after k_smax)

    k_pack_x<<<2048, 256, 0, stream>>>(x, xb, 8388608);
    k_transpose_w<<<768, 256, 0, stream>>>(w_qkv, wqT, 3072);
    k_transpose_w<<<256, 256, 0, stream>>>(w_proj, wpT, 1024);
    k_gemm<0><<<1536, 512, 0, stream>>>(xb, wqT, 12, qkT, v_tm, nullptr, nullptr);
    k_gram<<<2048, 512, 0, stream>>>(qkT, gram_part, sq_part);
    k_smax<<<2048, 256, 0, stream>>>(gram_part, sq_part, temperature, attn_g);
    k_wmix<<<512, 256, 0, stream>>>(attn_g, wpT, wmix);
    k_gemm<1><<<512, 512, 0, stream>>>(v_tm, wmix, 4, nullptr, nullptr, out, b_proj);
}

// Round 10
// 358.619 us; speedup vs baseline: 1.1617x; 1.0932x over previous
//
#include <hip/hip_runtime.h>
#include <cstdint>

typedef unsigned short u16;
typedef unsigned int u32;
typedef __attribute__((ext_vector_type(8))) short bf16x8;
typedef __attribute__((ext_vector_type(4))) float f32x4;

typedef const u32 __attribute__((address_space(1)))* gp_t;
typedef u32 __attribute__((address_space(3)))* lp_t;

__device__ __forceinline__ u16 f2bf(float f) {
    union { float f; u32 u; } v; v.f = f;
    u32 r = v.u + 0x7FFFu + ((v.u >> 16) & 1u);   // RNE
    return (u16)(r >> 16);
}
__device__ __forceinline__ float bf2f(u16 h) {
    union { u32 u; float f; } v; v.u = ((u32)h) << 16;
    return v.f;
}

// ---------------- pack x (fp32 -> bf16), vectorized (R6-proven) ----------------
__global__ void k_pack_x(const float* __restrict__ x, u16* __restrict__ xb, int n4) {
    int stride = gridDim.x * blockDim.x;
    for (int i = blockIdx.x * blockDim.x + threadIdx.x; i < n4; i += stride) {
        float4 v = ((const float4*)x)[i];
        ushort4 o;
        o.x = f2bf(v.x); o.y = f2bf(v.y); o.z = f2bf(v.z); o.w = f2bf(v.w);
        ((ushort4*)xb)[i] = o;
    }
}

// ---------------- transpose weight [1024][ncols] f32 -> [ncols][1024] bf16 ----
__global__ void k_transpose_w(const float* __restrict__ src, u16* __restrict__ dst, int ncols) {
    __shared__ float t[64][65];
    int ntn = ncols >> 6;
    int kb = (blockIdx.x / ntn) * 64;
    int nb = (blockIdx.x % ntn) * 64;
    for (int i = threadIdx.x; i < 4096; i += 256) {
        int r = i >> 6, c = i & 63;
        t[r][c] = src[(long)(kb + r) * ncols + nb + c];
    }
    __syncthreads();
    for (int i = threadIdx.x; i < 4096; i += 256) {
        int r = i >> 6, c = i & 63;
        dst[(long)(nb + r) * 1024 + kb + c] = f2bf(t[c][r]);
    }
}

// ---------------- pack Wv: wvb[cin][e] = bf16(w_qkv[cin][2048+e]) ----------------
__global__ __launch_bounds__(256) void k_pack_wv(const float* __restrict__ wqkv, u16* __restrict__ wvb) {
    const int idx = blockIdx.x * 256 + threadIdx.x;   // [0, 131072)
    const int cin = idx >> 7, e0 = (idx & 127) * 8;
    const float4 v1 = *(const float4*)(wqkv + (long)cin * 3072 + 2048 + e0);
    const float4 v2 = *(const float4*)(wqkv + (long)cin * 3072 + 2048 + e0 + 4);
    u16 u[8];
    u[0] = f2bf(v1.x); u[1] = f2bf(v1.y); u[2] = f2bf(v1.z); u[3] = f2bf(v1.w);
    u[4] = f2bf(v2.x); u[5] = f2bf(v2.y); u[6] = f2bf(v2.z); u[7] = f2bf(v2.w);
    *(uint4*)(wvb + (long)cin * 1024 + e0) = *(const uint4*)u;
}

// ---------------- 256x256 GEMM (R6-proven), BK=64, K=1024, qkT epilogue ----------
template<int EPI>
__global__ __launch_bounds__(512, 2) void k_gemm(
    const u16* __restrict__ A, const u16* __restrict__ Bt,
    int nTilesN,
    u16* __restrict__ qkT, u16* __restrict__ v_tm,
    float* __restrict__ outp, const float* __restrict__ bias)
{
    __shared__ uint4 smem4[8704];
    u16* sm = (u16*)smem4;

    const int tid = threadIdx.x;
    const int wid = tid >> 6, lane = tid & 63;
    const int wr = wid >> 2, wc = wid & 3;
    const int fr = lane & 15, sl = lane >> 4;

    const int nwg = gridDim.x;
    const int cpx = nwg >> 3;
    const int logical = (blockIdx.x & 7) * cpx + (blockIdx.x >> 3);

    const int bn = logical % nTilesN;
    const long m0 = (long)(logical / nTilesN) * 256;
    const int n0 = bn * 256;

    const int srow = wid * 32 + (lane >> 2);
    const int kswz = (((lane & 3) ^ ((srow >> 1) & 3)) << 3);
    const u16* gA = A + (m0 + srow) * 1024L + kswz;
    const u16* gB = Bt + ((long)n0 + srow) * 1024L + kswz;
    const int ldst = wid * 1024;

    const int fxor = ((sl ^ ((fr >> 1) & 3)) << 3);
    const int aBase = (wr * 128 + fr) * 32 + fxor;
    const int bBase = 32768 + (wc * 64 + fr) * 32 + fxor;

    f32x4 acc[8][4];
#pragma unroll
    for (int i = 0; i < 8; ++i)
#pragma unroll
        for (int j = 0; j < 4; ++j) acc[i][j] = (f32x4){0.f, 0.f, 0.f, 0.f};

#define STAGE_A(d, kh, ts) do { \
    const u16* g_ = gA + (ts) * 64 + (kh) * 32; \
    u16* l_ = sm + (d) * 16384 + (kh) * 8192 + ldst; \
    __builtin_amdgcn_global_load_lds((gp_t)g_, (lp_t)l_, 16, 0, 0); \
    __builtin_amdgcn_global_load_lds((gp_t)(g_ + 16 * 1024), (lp_t)(l_ + 512), 16, 0, 0); \
} while (0)
#define STAGE_B(d, kh, ts) do { \
    const u16* g_ = gB + (ts) * 64 + (kh) * 32; \
    u16* l_ = sm + 32768 + (d) * 16384 + (kh) * 8192 + ldst; \
    __builtin_amdgcn_global_load_lds((gp_t)g_, (lp_t)l_, 16, 0, 0); \
    __builtin_amdgcn_global_load_lds((gp_t)(g_ + 16 * 1024), (lp_t)(l_ + 512), 16, 0, 0); \
} while (0)

    STAGE_A(0, 0, 0); STAGE_B(0, 0, 0);
    STAGE_A(0, 1, 0); STAGE_B(0, 1, 0);
    STAGE_A(1, 0, 1); STAGE_B(1, 0, 1);
    asm volatile("s_waitcnt vmcnt(8)" ::: "memory");
    __builtin_amdgcn_s_barrier();

    bf16x8 afX[4], afY[4], bfX[4], bfY[4];
#pragma unroll
    for (int ni = 0; ni < 4; ++ni) bfX[ni] = *(const bf16x8*)(sm + bBase + ni * 512);
#pragma unroll
    for (int mi = 0; mi < 4; ++mi) afX[mi] = *(const bf16x8*)(sm + aBase + mi * 512);

#pragma unroll 2
    for (int T = 0; T < 16; ++T) {
        const int d = T & 1;
        const int t1 = (T + 1 < 16) ? T + 1 : 15;
        const int t2 = (T + 2 < 16) ? T + 2 : 15;
        const int base = d * 16384;
        const int nbase = (d ^ 1) * 16384;

#pragma unroll
        for (int mi = 0; mi < 4; ++mi)
            afY[mi] = *(const bf16x8*)(sm + aBase + (4 + mi) * 512 + base);
        STAGE_A(d ^ 1, 1, t1);
        asm volatile("s_waitcnt vmcnt(6)" ::: "memory");
        __builtin_amdgcn_s_barrier();
        __builtin_amdgcn_s_setprio(1);
#pragma unroll
        for (int mi = 0; mi < 4; ++mi)
#pragma unroll
            for (int ni = 0; ni < 4; ++ni)
                acc[mi][ni] = __builtin_amdgcn_mfma_f32_16x16x32_bf16(afX[mi], bfX[ni], acc[mi][ni], 0, 0, 0);
        __builtin_amdgcn_s_setprio(0);
        __builtin_amdgcn_s_barrier();

#pragma unroll
        for (int ni = 0; ni < 4; ++ni)
            bfY[ni] = *(const bf16x8*)(sm + bBase + ni * 512 + base + 8192);
#pragma unroll
        for (int mi = 0; mi < 4; ++mi)
            afX[mi] = *(const bf16x8*)(sm + aBase + mi * 512 + base + 8192);
        STAGE_B(d ^ 1, 1, t1);
        __builtin_amdgcn_s_barrier();
        __builtin_amdgcn_s_setprio(1);
#pragma unroll
        for (int mi = 0; mi < 4; ++mi)
#pragma unroll
            for (int ni = 0; ni < 4; ++ni)
                acc[mi + 4][ni] = __builtin_amdgcn_mfma_f32_16x16x32_bf16(afY[mi], bfX[ni], acc[mi + 4][ni], 0, 0, 0);
        __builtin_amdgcn_s_setprio(0);
        __builtin_amdgcn_s_barrier();

#pragma unroll
        for (int mi = 0; mi < 4; ++mi)
            afY[mi] = *(const bf16x8*)(sm + aBase + (4 + mi) * 512 + base + 8192);
        STAGE_A(d, 0, t2);
        asm volatile("s_waitcnt vmcnt(6)" ::: "memory");
        __builtin_amdgcn_s_barrier();
        __builtin_amdgcn_s_setprio(1);
#pragma unroll
        for (int mi = 0; mi < 4; ++mi)
#pragma unroll
            for (int ni = 0; ni < 4; ++ni)
                acc[mi][ni] = __builtin_amdgcn_mfma_f32_16x16x32_bf16(afX[mi], bfY[ni], acc[mi][ni], 0, 0, 0);
        __builtin_amdgcn_s_setprio(0);
        __builtin_amdgcn_s_barrier();

#pragma unroll
        for (int ni = 0; ni < 4; ++ni)
            bfX[ni] = *(const bf16x8*)(sm + bBase + ni * 512 + nbase);
#pragma unroll
        for (int mi = 0; mi < 4; ++mi)
            afX[mi] = *(const bf16x8*)(sm + aBase + mi * 512 + nbase);
        STAGE_B(d, 0, t2);
        __builtin_amdgcn_s_barrier();
        __builtin_amdgcn_s_setprio(1);
#pragma unroll
        for (int mi = 0; mi < 4; ++mi)
#pragma unroll
            for (int ni = 0; ni < 4; ++ni)
                acc[mi + 4][ni] = __builtin_amdgcn_mfma_f32_16x16x32_bf16(afY[mi], bfY[ni], acc[mi + 4][ni], 0, 0, 0);
        __builtin_amdgcn_s_setprio(0);
        __builtin_amdgcn_s_barrier();
    }
#undef STAGE_A
#undef STAGE_B
    asm volatile("s_waitcnt vmcnt(0)" ::: "memory");
    __syncthreads();

    if (EPI == 0) {
        const long b = m0 >> 12;
        const int tok0 = (int)(m0 & 4095);
        // q/k: per-wave transpose piece [64 ch][pitch 136 tok] bf16 (n0 < 2048 always)
        u16* piece = sm + wid * 8704;
#pragma unroll
        for (int mi = 0; mi < 8; ++mi)
#pragma unroll
            for (int ni = 0; ni < 4; ++ni) {
                const int ch = ni * 16 + fr;
                const int tk = mi * 16 + sl * 4;
                ushort4 w;
                w.x = f2bf(acc[mi][ni][0]); w.y = f2bf(acc[mi][ni][1]);
                w.z = f2bf(acc[mi][ni][2]); w.w = f2bf(acc[mi][ni][3]);
                *(ushort4*)(piece + ch * 136 + tk) = w;
            }
        __syncthreads();
#pragma unroll
        for (int i = 0; i < 16; ++i) {
            const int chunk = i * 512 + tid;
            const int row = chunk >> 4, c16 = chunk & 15;
            const int p = row >> 6, chl = row & 63;
            const int wrp = p >> 2, wcp = p & 3;
            const uint4 v = *(const uint4*)(sm + p * 8704 + chl * 136 + c16 * 8);
            *(uint4*)(qkT + ((b * 2048 + n0 + wcp * 64 + chl) * 4096L + tok0 + wrp * 128 + c16 * 8)) = v;
        }
    }
}

// ---------------- partial Gram + partial square-sums per (b,h,seg) (R6-proven) ----
__global__ __launch_bounds__(512, 2) void k_gram(
    const u16* __restrict__ qkT, float* __restrict__ gram_part, float* __restrict__ sq_part)
{
    __shared__ u16 lQ[64 * 256];
    __shared__ u16 lK[64 * 256];

    const int blk = blockIdx.x;
    const int seg = blk & 15;
    const int bh = blk >> 4;
    const int b = bh >> 4, h = bh & 15;
    const int tid = threadIdx.x;
    const int wid = tid >> 6, lane = tid & 63;

    {
        const int r2 = lane >> 5;
        const int slot = lane & 31;
        const int rbase = wid * 8;
#pragma unroll
        for (int i = 0; i < 4; ++i) {
            const int r = rbase + i * 2 + r2;
            const int col = seg * 256 + ((slot ^ (r & 7)) << 3);
            const u16* gq = qkT + ((long)(b * 2048 + h * 64 + r)) * 4096 + col;
            const u16* gk = qkT + ((long)(b * 2048 + 1024 + h * 64 + r)) * 4096 + col;
            __builtin_amdgcn_global_load_lds((gp_t)gq, (lp_t)(lQ + (rbase + i * 2) * 256), 16, 0, 0);
            __builtin_amdgcn_global_load_lds((gp_t)gk, (lp_t)(lK + (rbase + i * 2) * 256), 16, 0, 0);
        }
    }
    __syncthreads();

    {
        const int row = tid >> 2, q4 = tid & 3;
        const u16* src = (row < 64 ? lQ + row * 256 : lK + (row - 64) * 256) + q4 * 64;
        float s = 0.f;
#pragma unroll
        for (int i = 0; i < 8; ++i) {
            uint4 v = *(const uint4*)(src + i * 8);
            float a0, a1;
            a0 = bf2f((u16)(v.x & 0xFFFF)); a1 = bf2f((u16)(v.x >> 16)); s += a0 * a0 + a1 * a1;
            a0 = bf2f((u16)(v.y & 0xFFFF)); a1 = bf2f((u16)(v.y >> 16)); s += a0 * a0 + a1 * a1;
            a0 = bf2f((u16)(v.z & 0xFFFF)); a1 = bf2f((u16)(v.z >> 16)); s += a0 * a0 + a1 * a1;
            a0 = bf2f((u16)(v.w & 0xFFFF)); a1 = bf2f((u16)(v.w >> 16)); s += a0 * a0 + a1 * a1;
        }
        s += __shfl_xor(s, 1);
        s += __shfl_xor(s, 2);
        if (q4 == 0) sq_part[(long)blk * 128 + row] = s;
    }

    const int mrow = wid >> 1, npair = wid & 1;
    const int fr = lane & 15, sl = lane >> 4;
    f32x4 acc[2];
    acc[0] = (f32x4){0.f, 0.f, 0.f, 0.f};
    acc[1] = (f32x4){0.f, 0.f, 0.f, 0.f};
#pragma unroll
    for (int ks = 0; ks < 8; ++ks) {
        const int ra = mrow * 16 + fr;
        const bf16x8 a = *(const bf16x8*)(lQ + ra * 256 + (((ks * 4 + sl) ^ (ra & 7)) << 3));
#pragma unroll
        for (int ni = 0; ni < 2; ++ni) {
            const int rb = npair * 32 + ni * 16 + fr;
            const bf16x8 bb = *(const bf16x8*)(lK + rb * 256 + (((ks * 4 + sl) ^ (rb & 7)) << 3));
            acc[ni] = __builtin_amdgcn_mfma_f32_16x16x32_bf16(a, bb, acc[ni], 0, 0, 0);
        }
    }
    float* gp = gram_part + (long)blk * 4096;
#pragma unroll
    for (int ni = 0; ni < 2; ++ni)
#pragma unroll
        for (int r = 0; r < 4; ++r)
            gp[(mrow * 16 + sl * 4 + r) * 64 + npair * 32 + ni * 16 + fr] = acc[ni][r];
}

// ---------------- reduce partials + normalize + softmax -> attn bf16 (R6-proven) --
__global__ __launch_bounds__(256) void k_smax(
    const float* __restrict__ gram_part, const float* __restrict__ sq_part,
    const float* __restrict__ temperature, u16* __restrict__ attn_g)
{
    const int row = blockIdx.x * 4 + (threadIdx.x >> 6);
    const int e = threadIdx.x & 63;
    const int bh = row >> 6, d = row & 63;
    const int h = bh & 15;
    float raw = 0.f, sqq = 0.f, sqk = 0.f;
    const float* gp = gram_part + (long)bh * 16 * 4096 + d * 64 + e;
    const float* sp = sq_part + (long)bh * 16 * 128;
#pragma unroll
    for (int s = 0; s < 16; ++s) {
        raw += gp[s * 4096];
        sqq += sp[s * 128 + d];
        sqk += sp[s * 128 + 64 + e];
    }
    const float rq = 1.f / fmaxf(sqrtf(sqq), 1e-12f);
    const float rk = 1.f / fmaxf(sqrtf(sqk), 1e-12f);
    const float v = raw * rq * rk * temperature[h];
    float mx = v;
#pragma unroll
    for (int o = 32; o; o >>= 1) mx = fmaxf(mx, __shfl_xor(mx, o));
    const float p = __expf(v - mx);
    float sum = p;
#pragma unroll
    for (int o = 32; o; o >>= 1) sum += __shfl_xor(sum, o);
    attn_g[(long)row * 64 + e] = f2bf(p / sum);
}

// ---------------- fold attn into w_proj (R6-proven) ------------------------------
__global__ __launch_bounds__(256) void k_wmix(
    const u16* __restrict__ attn_g, const u16* __restrict__ wpT, u16* __restrict__ wmix)
{
    __shared__ u16 lA[64 * 72];
    __shared__ u16 lB[256 * 64];

    const int blk = blockIdx.x;
    const int nseg = blk & 3, bh = blk >> 2;
    const int b = bh >> 4, h = bh & 15;
    const int tid = threadIdx.x;
    const int wid = tid >> 6, lane = tid & 63;
    const int fr = lane & 15, sl = lane >> 4;

#pragma unroll
    for (int i = 0; i < 8; ++i) {
        const int cc = wid * 8 + i;
        const int row = cc * 8 + (lane >> 3);
        const int slot = lane & 7;
        const u16* g = wpT + (long)(nseg * 256 + row) * 1024 + h * 64 + ((slot ^ (row & 7)) << 3);
        __builtin_amdgcn_global_load_lds((gp_t)g, (lp_t)(lB + cc * 512), 16, 0, 0);
    }
    {
        const u16* src = attn_g + (long)bh * 4096;
        for (int i = tid; i < 4096; i += 256) {
            const int d = i >> 6, e = i & 63;
            lA[e * 72 + d] = src[i];
        }
    }
    __syncthreads();

    f32x4 acc[4][4];
#pragma unroll
    for (int i = 0; i < 4; ++i)
#pragma unroll
        for (int j = 0; j < 4; ++j) acc[i][j] = (f32x4){0.f, 0.f, 0.f, 0.f};

#pragma unroll
    for (int ks = 0; ks < 2; ++ks) {
        bf16x8 a[4], bb[4];
#pragma unroll
        for (int mi = 0; mi < 4; ++mi)
            a[mi] = *(const bf16x8*)(lA + (mi * 16 + fr) * 72 + ks * 32 + sl * 8);
#pragma unroll
        for (int ni = 0; ni < 4; ++ni) {
            const int rb = wid * 64 + ni * 16 + fr;
            bb[ni] = *(const bf16x8*)(lB + rb * 64 + (((ks * 4 + sl) ^ (rb & 7)) << 3));
        }
#pragma unroll
        for (int mi = 0; mi < 4; ++mi)
#pragma unroll
            for (int ni = 0; ni < 4; ++ni)
                acc[mi][ni] = __builtin_amdgcn_mfma_f32_16x16x32_bf16(a[mi], bb[ni], acc[mi][ni], 0, 0, 0);
    }

    u16* dst = wmix + ((long)b << 20);
#pragma unroll
    for (int mi = 0; mi < 4; ++mi)
#pragma unroll
        for (int ni = 0; ni < 4; ++ni) {
            const int cout = nseg * 256 + wid * 64 + ni * 16 + fr;
            const int e0 = mi * 16 + sl * 4;
            ushort4 w;
            w.x = f2bf(acc[mi][ni][0]); w.y = f2bf(acc[mi][ni][1]);
            w.z = f2bf(acc[mi][ni][2]); w.w = f2bf(acc[mi][ni][3]);
            *(ushort4*)(dst + (long)cout * 1024 + h * 64 + e0) = w;
        }
}

// ---------------- 128x128 GEMM (R1-proven structure), BK=32, batched -------------
__global__ __launch_bounds__(256) void k_g128(
    const u16* __restrict__ A, long Ab, const u16* __restrict__ Bt, long Bs,
    u16* __restrict__ C, long Cb, int K, int MT, int NT)
{
    __shared__ u16 sm[8192];
    __shared__ u16 lC[128 * 136];

    const int tid = threadIdx.x;
    const int wid = tid >> 6, lane = tid & 63;
    const int wr = wid >> 1, wc = wid & 1;
    const int fr = lane & 15, sl = lane >> 4;

    const int nwg = gridDim.x;
    const int logical = (blockIdx.x & 7) * (nwg >> 3) + (blockIdx.x >> 3);

    const int b = logical / (MT * NT);
    const int r = logical % (MT * NT);
    const int i0 = r / NT, j0 = r % NT;
    const int m0 = i0 * 128, n0 = j0 * 128;
    const u16* Abp = A + (long)b * Ab;
    const u16* Bbp = Bt + (long)b * Bs;
    u16* Cbp = C + (long)b * Cb;

    const int srow = lane >> 2;
    const int sslot = lane & 3;

    f32x4 acc[4][4];
#pragma unroll
    for (int i = 0; i < 4; ++i)
#pragma unroll
        for (int j = 0; j < 4; ++j) acc[i][j] = (f32x4){0.f, 0.f, 0.f, 0.f};

    for (int kt = 0; kt < K; kt += 32) {
        __syncthreads();
#pragma unroll
        for (int i = 0; i < 2; ++i) {
            const int row = wid * 32 + i * 16 + srow;
            const int swz = (sslot ^ ((row >> 1) & 3)) << 3;
            const u16* ga = Abp + (long)(m0 + row) * K + kt + swz;
            const u16* gb = Bbp + (long)(n0 + row) * K + kt + swz;
            __builtin_amdgcn_global_load_lds((gp_t)ga, (lp_t)(sm + (wid * 2 + i) * 512), 16, 0, 0);
            __builtin_amdgcn_global_load_lds((gp_t)gb, (lp_t)(sm + 4096 + (wid * 2 + i) * 512), 16, 0, 0);
        }
        __syncthreads();
        bf16x8 af[4], bfr[4];
#pragma unroll
        for (int mi = 0; mi < 4; ++mi) {
            const int row = wr * 64 + mi * 16 + fr;
            af[mi] = *(const bf16x8*)(sm + row * 32 + ((sl ^ ((row >> 1) & 3)) << 3));
        }
#pragma unroll
        for (int ni = 0; ni < 4; ++ni) {
            const int row = wc * 64 + ni * 16 + fr;
            bfr[ni] = *(const bf16x8*)(sm + 4096 + row * 32 + ((sl ^ ((row >> 1) & 3)) << 3));
        }
#pragma unroll
        for (int mi = 0; mi < 4; ++mi)
#pragma unroll
            for (int ni = 0; ni < 4; ++ni)
                acc[mi][ni] = __builtin_amdgcn_mfma_f32_16x16x32_bf16(af[mi], bfr[ni], acc[mi][ni], 0, 0, 0);
    }
    __syncthreads();

#pragma unroll
    for (int mi = 0; mi < 4; ++mi)
#pragma unroll
        for (int ni = 0; ni < 4; ++ni) {
            const int ch = wc * 64 + ni * 16 + fr;
            const int tk = wr * 64 + mi * 16 + sl * 4;
#pragma unroll
            for (int rr = 0; rr < 4; ++rr)
                lC[(tk + rr) * 136 + ch] = f2bf(acc[mi][ni][rr]);
        }
    __syncthreads();
    {
        const int tk = tid >> 1, half = tid & 1;
        const u16* sp = lC + tk * 136 + half * 64;
        u16* dp = Cbp + (long)(m0 + tk) * 1024 + n0 + half * 64;
#pragma unroll
        for (int i = 0; i < 8; ++i) ((uint4*)dp)[i] = ((const uint4*)sp)[i];   // FIXED: 8x16B = full 64-elem half
    }
}

// ---------------- 256x256 GEMM final: out = A @ Bt^T + bias (f32 out) ------------
__global__ __launch_bounds__(512, 2) void k_gemm256f(
    const u16* __restrict__ A, long Ab, const u16* __restrict__ Bt, long Bs,
    int MT, int NT, float* __restrict__ cF, long Cb, const float* __restrict__ bias)
{
    __shared__ uint4 smem4[8704];
    u16* sm = (u16*)smem4;

    const int tid = threadIdx.x;
    const int wid = tid >> 6, lane = tid & 63;
    const int wr = wid >> 2, wc = wid & 3;
    const int fr = lane & 15, sl = lane >> 4;

    const int nwg = gridDim.x;
    const int logical = (blockIdx.x & 7) * (nwg >> 3) + (blockIdx.x >> 3);
    const int b = logical / (MT * NT);
    const int rem = logical % (MT * NT);
    const int mt = rem / NT, nt = rem % NT;
    const long m0 = (long)mt * 256;
    const int n0 = nt * 256;

    const int srow = wid * 32 + (lane >> 2);
    const int kswz = (((lane & 3) ^ ((srow >> 1) & 3)) << 3);
    const u16* gA = A + (long)b * Ab + (m0 + srow) * 1024L + kswz;
    const u16* gB = Bt + (long)b * Bs + ((long)n0 + srow) * 1024L + kswz;
    const int ldst = wid * 1024;

    const int fxor = ((sl ^ ((fr >> 1) & 3)) << 3);
    const int aBase = (wr * 128 + fr) * 32 + fxor;
    const int bBase = 32768 + (wc * 64 + fr) * 32 + fxor;

    f32x4 acc[8][4];
#pragma unroll
    for (int i = 0; i < 8; ++i)
#pragma unroll
        for (int j = 0; j < 4; ++j) acc[i][j] = (f32x4){0.f, 0.f, 0.f, 0.f};

#define STAGE_A(d, kh, ts) do { \
    const u16* g_ = gA + (ts) * 64 + (kh) * 32; \
    u16* l_ = sm + (d) * 16384 + (kh) * 8192 + ldst; \
    __builtin_amdgcn_global_load_lds((gp_t)g_, (lp_t)l_, 16, 0, 0); \
    __builtin_amdgcn_global_load_lds((gp_t)(g_ + 16 * 1024), (lp_t)(l_ + 512), 16, 0, 0); \
} while (0)
#define STAGE_B(d, kh, ts) do { \
    const u16* g_ = gB + (ts) * 64 + (kh) * 32; \
    u16* l_ = sm + 32768 + (d) * 16384 + (kh) * 8192 + ldst; \
    __builtin_amdgcn_global_load_lds((gp_t)g_, (lp_t)l_, 16, 0, 0); \
    __builtin_amdgcn_global_load_lds((gp_t)(g_ + 16 * 1024), (lp_t)(l_ + 512), 16, 0, 0); \
} while (0)

    STAGE_A(0, 0, 0); STAGE_B(0, 0, 0);
    STAGE_A(0, 1, 0); STAGE_B(0, 1, 0);
    STAGE_A(1, 0, 1); STAGE_B(1, 0, 1);
    asm volatile("s_waitcnt vmcnt(8)" ::: "memory");
    __builtin_amdgcn_s_barrier();

    bf16x8 afX[4], afY[4], bfX[4], bfY[4];
#pragma unroll
    for (int ni = 0; ni < 4; ++ni) bfX[ni] = *(const bf16x8*)(sm + bBase + ni * 512);
#pragma unroll
    for (int mi = 0; mi < 4; ++mi) afX[mi] = *(const bf16x8*)(sm + aBase + mi * 512);

#pragma unroll 2
    for (int T = 0; T < 16; ++T) {
        const int d = T & 1;
        const int t1 = (T + 1 < 16) ? T + 1 : 15;
        const int t2 = (T + 2 < 16) ? T + 2 : 15;
        const int base = d * 16384;
        const int nbase = (d ^ 1) * 16384;

#pragma unroll
        for (int mi = 0; mi < 4; ++mi)
            afY[mi] = *(const bf16x8*)(sm + aBase + (4 + mi) * 512 + base);
        STAGE_A(d ^ 1, 1, t1);
        asm volatile("s_waitcnt vmcnt(6)" ::: "memory");
        __builtin_amdgcn_s_barrier();
        __builtin_amdgcn_s_setprio(1);
#pragma unroll
        for (int mi = 0; mi < 4; ++mi)
#pragma unroll
            for (int ni = 0; ni < 4; ++ni)
                acc[mi][ni] = __builtin_amdgcn_mfma_f32_16x16x32_bf16(afX[mi], bfX[ni], acc[mi][ni], 0, 0, 0);
        __builtin_amdgcn_s_setprio(0);
        __builtin_amdgcn_s_barrier();

#pragma unroll
        for (int ni = 0; ni < 4; ++ni)
            bfY[ni] = *(const bf16x8*)(sm + bBase + ni * 512 + base + 8192);
#pragma unroll
        for (int mi = 0; mi < 4; ++mi)
            afX[mi] = *(const bf16x8*)(sm + aBase + mi * 512 + base + 8192);
        STAGE_B(d ^ 1, 1, t1);
        __builtin_amdgcn_s_barrier();
        __builtin_amdgcn_s_setprio(1);
#pragma unroll
        for (int mi = 0; mi < 4; ++mi)
#pragma unroll
            for (int ni = 0; ni < 4; ++ni)
                acc[mi + 4][ni] = __builtin_amdgcn_mfma_f32_16x16x32_bf16(afY[mi], bfX[ni], acc[mi + 4][ni], 0, 0, 0);
        __builtin_amdgcn_s_setprio(0);
        __builtin_amdgcn_s_barrier();

#pragma unroll
        for (int mi = 0; mi < 4; ++mi)
            afY[mi] = *(const bf16x8*)(sm + aBase + (4 + mi) * 512 + base + 8192);
        STAGE_A(d, 0, t2);
        asm volatile("s_waitcnt vmcnt(6)" ::: "memory");
        __builtin_amdgcn_s_barrier();
        __builtin_amdgcn_s_setprio(1);
#pragma unroll
        for (int mi = 0; mi < 4; ++mi)
#pragma unroll
            for (int ni = 0; ni < 4; ++ni)
                acc[mi][ni] = __builtin_amdgcn_mfma_f32_16x16x32_bf16(afX[mi], bfY[ni], acc[mi][ni], 0, 0, 0);
        __builtin_amdgcn_s_setprio(0);
        __builtin_amdgcn_s_barrier();

#pragma unroll
        for (int ni = 0; ni < 4; ++ni)
            bfX[ni] = *(const bf16x8*)(sm + bBase + ni * 512 + nbase);
#pragma unroll
        for (int mi = 0; mi < 4; ++mi)
            afX[mi] = *(const bf16x8*)(sm + aBase + mi * 512 + nbase);
        STAGE_B(d, 0, t2);
        __builtin_amdgcn_s_barrier();
        __builtin_amdgcn_s_setprio(1);
#pragma unroll
        for (int mi = 0; mi < 4; ++mi)
#pragma unroll
            for (int ni = 0; ni < 4; ++ni)
                acc[mi + 4][ni] = __builtin_amdgcn_mfma_f32_16x16x32_bf16(afY[mi], bfY[ni], acc[mi + 4][ni], 0, 0, 0);
        __builtin_amdgcn_s_setprio(0);
        __builtin_amdgcn_s_barrier();
    }
#undef STAGE_A
#undef STAGE_B
    asm volatile("s_waitcnt vmcnt(0)" ::: "memory");
    __syncthreads();

    float* cbase = cF + (long)b * Cb;
    float bi[4];
#pragma unroll
    for (int ni = 0; ni < 4; ++ni) bi[ni] = bias[n0 + wc * 64 + ni * 16 + fr];
#pragma unroll
    for (int pass = 0; pass < 2; ++pass) {
        float* pieceF = (float*)smem4 + wid * 4352;
        if (pass) __syncthreads();
#pragma unroll
        for (int mi2 = 0; mi2 < 4; ++mi2) {
            const int mi = pass * 4 + mi2;
#pragma unroll
            for (int ni = 0; ni < 4; ++ni) {
                const int ch = ni * 16 + fr;
                const int tk = mi2 * 16 + sl * 4;
#pragma unroll
                for (int rr = 0; rr < 4; ++rr)
                    pieceF[(tk + rr) * 68 + ch] = acc[mi][ni][rr] + bi[ni];
            }
        }
        __syncthreads();
#pragma unroll
        for (int i = 0; i < 16; ++i) {
            const int chunk = i * 512 + tid;
            const int row = chunk >> 4, c4 = chunk & 15;
            const int p = row >> 6, tk = row & 63;
            const int wrp = p >> 2, wcp = p & 3;
            const float4 v = *(const float4*)((float*)smem4 + p * 4352 + tk * 68 + c4 * 4);
            *(float4*)(cbase + (m0 + wrp * 128 + pass * 64 + tk) * 1024L + n0 + wcp * 64 + c4 * 4) = v;
        }
    }
}

// ---------------- launch ----------------
extern "C" void kernel_launch(void* const* d_in, const int* in_sizes, int n_in,
                              void* d_out, int out_size, void* d_ws, size_t ws_size,
                              hipStream_t stream) {
    const float* x = (const float*)d_in[0];
    const float* w_qkv = (const float*)d_in[1];
    const float* temperature = (const float*)d_in[2];
    const float* w_proj = (const float*)d_in[3];
    const float* b_proj = (const float*)d_in[4];
    float* out = (float*)d_out;
    char* ws = (char*)d_ws;

    u16* wqT    = (u16*)(ws);                       //   6,291,456 B [3072][1024] bf16
    u16* wpT    = (u16*)(ws + 6291456);             //   2,097,152 B [1024][1024] bf16
    u16* wvb    = (u16*)(ws + 8388608);             //   2,097,152 B [1024][1024] bf16
    u16* xt     = (u16*)(ws + 10485760);            //  67,108,864 B [32768][1024] bf16
    u16* qkT    = (u16*)(ws + 77594624);            // 134,217,728 B [8][2048][4096] bf16
    float* gram_part = (float*)(ws + 211812352);    //  33,554,432 B [2048][64][64] f32
    float* sq_part   = (float*)(ws + 245366784);    //   1,048,576 B [2048][128] f32
    u16* attn_g = (u16*)(ws + 246415360);           //   1,048,576 B [128][64][64] bf16
    u16* wmix   = (u16*)(ws + 247463936);           //  16,777,216 B [8][1024][1024] bf16
    u16* wfinT  = (u16*)(ws + 211812352);           //  16,777,216 B (overlays gram_part, dead after k_smax)

    k_pack_x<<<2048, 256, 0, stream>>>(x, xt, 8388608);
    k_transpose_w<<<768, 256, 0, stream>>>(w_qkv, wqT, 3072);
    k_transpose_w<<<256, 256, 0, stream>>>(w_proj, wpT, 1024);
    k_pack_wv<<<512, 256, 0, stream>>>(w_qkv, wvb);
    // q,k only: 128 m-tiles x 8 n-tiles
    k_gemm<0><<<1024, 512, 0, stream>>>(xt, wqT, 8, qkT, nullptr, nullptr, nullptr);
    k_gram<<<2048, 512, 0, stream>>>(qkT, gram_part, sq_part);
    k_smax<<<2048, 256, 0, stream>>>(gram_part, sq_part, temperature, attn_g);
    k_wmix<<<512, 256, 0, stream>>>(attn_g, wpT, wmix);
    // wfinT_b[cout][cin] = sum_e wmix_b[cout][e] * wvb[cin][e]
    k_g128<<<512, 256, 0, stream>>>(wmix, 1048576L, wvb, 0L, wfinT, 1048576L, 1024, 8, 8);
    // out = xt @ wfinT_b^T + bias
    k_gemm256f<<<512, 512, 0, stream>>>(xt, 4194304L, wfinT, 1048576L, 16, 4, out, 4194304L, b_proj);
}